// Round 5
// baseline (7114.355 us; speedup 1.0000x reference)
//
#include <hip/hip_runtime.h>
#include <hip/hip_bf16.h>
#include <hip/hip_fp16.h>

#define HD    256
#define TENC  15
#define PLEN  45
#define MROW  32
#define NTHR  512
#define NBLK  (32768 / MROW)   // 1024 blocks, ~4 per CU over kernel, 2 resident

typedef __attribute__((ext_vector_type(16))) float f32x16;
typedef __attribute__((ext_vector_type(8)))  short bf16x8;

#define MFMA32 __builtin_amdgcn_mfma_f32_32x32x16_bf16

__device__ __forceinline__ unsigned short f2bf(float f) {
    union { float f; unsigned int u; } v; v.f = f;
    unsigned int r = v.u + 0x7FFF + ((v.u >> 16) & 1);  // RNE
    return (unsigned short)(r >> 16);
}

__global__ void cvt_bf16_kernel(const float* __restrict__ src,
                                unsigned short* __restrict__ dst, int n) {
    int i = blockIdx.x * blockDim.x + threadIdx.x;
    if (i < n) dst[i] = f2bf(src[i]);
}

// out_W padded to [32][256] bf16 (rows 4..31 zero)
__global__ void pad_outw_kernel(const float* __restrict__ src,
                                unsigned short* __restrict__ dst) {
    int i = blockIdx.x * blockDim.x + threadIdx.x;
    if (i < 32 * HD) dst[i] = (i < 4 * HD) ? f2bf(src[i]) : (unsigned short)0;
}

// Swizzled byte offset into a [32][256] bf16 LDS tile (row stride 512B = 32
// 16B chunks). chunk ^= row is a bijection per row; a 32x32 A-frag read
// (lanes 0..31 distinct rows, same chunk) then hits each 16B slot exactly
// twice across 64 lanes -> 2 lanes/bank = conflict-free (m136).
__device__ __forceinline__ int swz32(int row, int col) {
    return row * 512 + ((((col >> 3) ^ row) & 31) << 4) + ((col & 7) << 1);
}

__global__ __launch_bounds__(NTHR, 4) void gru_main(
    const float* __restrict__ x,
    const float* __restrict__ eW, const float* __restrict__ eb,
    const unsigned short* __restrict__ encWih, const unsigned short* __restrict__ encWhh,
    const float* __restrict__ enc_bih, const float* __restrict__ enc_bhh,
    const unsigned short* __restrict__ decEW, const float* __restrict__ dec_eb,
    const unsigned short* __restrict__ decWih, const unsigned short* __restrict__ decWhh,
    const float* __restrict__ dec_bih, const float* __restrict__ dec_bhh,
    const unsigned short* __restrict__ outWp, const float* __restrict__ outb,
    float* __restrict__ out)
{
    __shared__ __align__(16) unsigned short ls_a[MROW * HD];  // 16KB swizzled bf16
    __shared__ __align__(16) unsigned short ls_h[MROW * HD];  // 16KB swizzled bf16
    __shared__ float ls_ew[HD * 4];
    __shared__ float ls_eb[HD];
    __shared__ float ls_bias[4 * HD];   // bR, bZ, bN(ih), bH(hh)
    __shared__ float ls_deb[HD];

    const int tid   = threadIdx.x;
    const int lane  = tid & 63;
    const int wv    = tid >> 6;      // 0..7
    const int cb    = wv * 32;       // wave's 32 output columns
    const int rowA  = lane & 31;     // A-row / B-col within 32x32 tile
    const int hi    = lane >> 5;     // k-half (0/1)
    const int col   = cb + rowA;     // this lane's C/D column
    const int nbase = blockIdx.x * MROW;

    for (int i = tid; i < HD * 4; i += NTHR) ls_ew[i] = eW[i];
    if (tid < HD) {
        ls_eb[tid]            = eb[tid];
        ls_bias[tid]          = enc_bih[tid] + enc_bhh[tid];
        ls_bias[HD + tid]     = enc_bih[HD + tid] + enc_bhh[HD + tid];
        ls_bias[2 * HD + tid] = enc_bih[2 * HD + tid];
        ls_bias[3 * HD + tid] = enc_bhh[2 * HD + tid];
    }
    for (int i = tid; i < MROW * HD / 2; i += NTHR) ((unsigned int*)ls_h)[i] = 0u;

    // h carried as packed fp16 pairs (rows q, q+1 of the C/D layout).
    __half2 hpk[8];
    #pragma unroll
    for (int i = 0; i < 8; ++i) hpk[i] = __floats2half2_rn(0.f, 0.f);

    f32x16 accR, accZ, accN1, accN2;

    const char* pa = (const char*)ls_a + rowA * 512;
    const char* ph = (const char*)ls_h + rowA * 512;

    // acc{R,Z} += x@Wr/z + h@Ur/z ; accN1 += x@Wn ; accN2 += h@Un
    // W layout: [768][256] bf16 row-major, gate segments at +0 / +65536 / +131072 elems.
    auto gates = [&](const unsigned short* __restrict__ Wih,
                     const unsigned short* __restrict__ Whh) {
        accR = {}; accZ = {}; accN1 = {}; accN2 = {};
        const unsigned short* wi = Wih + (size_t)col * HD + hi * 8;
        const unsigned short* wh = Whh + (size_t)col * HD + hi * 8;
        #pragma unroll 4
        for (int kk = 0; kk < 16; ++kk) {
            const int sh = (((kk * 2 + hi) ^ rowA) & 31) << 4;
            bf16x8 a1 = *(const bf16x8*)(pa + sh);
            bf16x8 a2 = *(const bf16x8*)(ph + sh);
            bf16x8 b0 = *(const bf16x8*)(wi + kk * 16);
            bf16x8 b1 = *(const bf16x8*)(wh + kk * 16);
            accR = MFMA32(a1, b0, accR, 0, 0, 0);
            accR = MFMA32(a2, b1, accR, 0, 0, 0);
            bf16x8 b2 = *(const bf16x8*)(wi + kk * 16 + 65536);
            bf16x8 b3 = *(const bf16x8*)(wh + kk * 16 + 65536);
            accZ = MFMA32(a1, b2, accZ, 0, 0, 0);
            accZ = MFMA32(a2, b3, accZ, 0, 0, 0);
            bf16x8 b4 = *(const bf16x8*)(wi + kk * 16 + 131072);
            bf16x8 b5 = *(const bf16x8*)(wh + kk * 16 + 131072);
            accN1 = MFMA32(a1, b4, accN1, 0, 0, 0);
            accN2 = MFMA32(a2, b5, accN2, 0, 0, 0);
        }
    };

    // C/D layout (32x32): col = lane&31 (fixed per lane), row = (q&3)+8*(q>>2)+4*hi
    auto update = [&]() {
        const float bR = ls_bias[col];
        const float bZ = ls_bias[HD + col];
        const float bN = ls_bias[2 * HD + col];
        const float bH = ls_bias[3 * HD + col];
        #pragma unroll
        for (int q = 0; q < 16; q += 2) {
            float2 hv = __half22float2(hpk[q >> 1]);
            float hn0, hn1;
            {
                float rr  = 1.f / (1.f + __expf(-(accR[q] + bR)));
                float zz  = 1.f / (1.f + __expf(-(accZ[q] + bZ)));
                float pre = accN1[q] + bN + rr * (accN2[q] + bH);
                float nn  = 2.f / (1.f + __expf(-2.f * pre)) - 1.f;
                hn0 = (1.f - zz) * nn + zz * hv.x;
            }
            {
                float rr  = 1.f / (1.f + __expf(-(accR[q + 1] + bR)));
                float zz  = 1.f / (1.f + __expf(-(accZ[q + 1] + bZ)));
                float pre = accN1[q + 1] + bN + rr * (accN2[q + 1] + bH);
                float nn  = 2.f / (1.f + __expf(-2.f * pre)) - 1.f;
                hn1 = (1.f - zz) * nn + zz * hv.y;
            }
            hpk[q >> 1] = __floats2half2_rn(hn0, hn1);
        }
    };

    auto write_h = [&]() {
        #pragma unroll
        for (int q = 0; q < 16; q += 2) {
            float2 hv = __half22float2(hpk[q >> 1]);
            int row0 = (q & 3) + ((q >> 2) << 3) + (hi << 2);
            *(unsigned short*)((char*)ls_h + swz32(row0, col))     = f2bf(hv.x);
            *(unsigned short*)((char*)ls_h + swz32(row0 + 1, col)) = f2bf(hv.y);
        }
    };

    auto embed_step = [&](int t) {
        int row = tid & 31;
        int c0  = (tid >> 5) * 16;
        const float4 xv = *(const float4*)(x + ((size_t)(nbase + row) * TENC + t) * 4);
        #pragma unroll 4
        for (int j = 0; j < 16; ++j) {
            int c = c0 + j;
            const float* wp = &ls_ew[c * 4];
            float v = fmaf(xv.x, wp[0], fmaf(xv.y, wp[1],
                      fmaf(xv.z, wp[2], fmaf(xv.w, wp[3], ls_eb[c]))));
            *(unsigned short*)((char*)ls_a + swz32(row, c)) = f2bf(fmaxf(v, 0.f));
        }
    };

    // dec_in = relu(h @ dec_embed_W^T + deb) -> ls_a
    auto dec_embed = [&]() {
        f32x16 o = {};
        const unsigned short* we = decEW + (size_t)col * HD + hi * 8;
        #pragma unroll 4
        for (int kk = 0; kk < 16; ++kk) {
            const int sh = (((kk * 2 + hi) ^ rowA) & 31) << 4;
            bf16x8 a = *(const bf16x8*)(ph + sh);
            bf16x8 b = *(const bf16x8*)(we + kk * 16);
            o = MFMA32(a, b, o, 0, 0, 0);
        }
        const float db = ls_deb[col];
        #pragma unroll
        for (int q = 0; q < 16; ++q) {
            int row = (q & 3) + ((q >> 2) << 3) + (hi << 2);
            *(unsigned short*)((char*)ls_a + swz32(row, col)) = f2bf(fmaxf(o[q] + db, 0.f));
        }
    };

    // out = h @ out_W^T + out_b, one wave, 32x32 MFMA (cols 4..31 of outWp are zero)
    auto out_layer = [&](int t) {
        if (wv == 0) {
            f32x16 o = {};
            const unsigned short* wo = outWp + (size_t)rowA * HD + hi * 8;
            #pragma unroll 4
            for (int kk = 0; kk < 16; ++kk) {
                const int sh = (((kk * 2 + hi) ^ rowA) & 31) << 4;
                bf16x8 a = *(const bf16x8*)(ph + sh);
                bf16x8 b = *(const bf16x8*)(wo + kk * 16);
                o = MFMA32(a, b, o, 0, 0, 0);
            }
            if (rowA < 4) {
                const float bo = outb[rowA];
                #pragma unroll
                for (int q = 0; q < 16; ++q) {
                    int row = (q & 3) + ((q >> 2) << 3) + (hi << 2);
                    out[((size_t)(nbase + row) * PLEN + t) * 4 + rowA] = o[q] + bo;
                }
            }
        }
    };

    // ---- prologue ----
    __syncthreads();             // staging + ls_h zero visible
    embed_step(0);
    __syncthreads();             // ls_a ready

    // ---- encoder: 2 barriers/step ----
    for (int t = 0; t < TENC; ++t) {
        gates(encWih, encWhh);
        update();
        __syncthreads();         // all ls_a/ls_h reads done
        write_h();
        if (t + 1 < TENC) embed_step(t + 1);
        __syncthreads();         // new h + next embed visible
    }

    // ---- encoder -> decoder transition ----
    if (tid < HD) {
        ls_bias[tid]          = dec_bih[tid] + dec_bhh[tid];
        ls_bias[HD + tid]     = dec_bih[HD + tid] + dec_bhh[HD + tid];
        ls_bias[2 * HD + tid] = dec_bih[2 * HD + tid];
        ls_bias[3 * HD + tid] = dec_bhh[2 * HD + tid];
        ls_deb[tid]           = dec_eb[tid];
    }
    __syncthreads();
    dec_embed();                 // dec_in0 from h_enc
    __syncthreads();

    // ---- decoder: 3 barriers/step ----
    for (int t = 0; t < PLEN; ++t) {
        gates(decWih, decWhh);   // reads ls_a (dec_in t), ls_h (h_{t-1})
        update();
        __syncthreads();         // B1: reads done
        write_h();               // h_t
        __syncthreads();         // B2: h_t visible
        dec_embed();             // dec_in t+1 -> ls_a
        out_layer(t);            // out_t from h_t
        __syncthreads();         // B3: ls_a ready
    }
}

extern "C" void kernel_launch(void* const* d_in, const int* in_sizes, int n_in,
                              void* d_out, int out_size, void* d_ws, size_t ws_size,
                              hipStream_t stream) {
    const float* x       = (const float*)d_in[0];
    const float* eW      = (const float*)d_in[1];
    const float* eb      = (const float*)d_in[2];
    const float* encWih  = (const float*)d_in[3];
    const float* encWhh  = (const float*)d_in[4];
    const float* enc_bih = (const float*)d_in[5];
    const float* enc_bhh = (const float*)d_in[6];
    const float* decEWf  = (const float*)d_in[7];
    const float* dec_eb  = (const float*)d_in[8];
    const float* decWihf = (const float*)d_in[9];
    const float* decWhhf = (const float*)d_in[10];
    const float* dec_bih = (const float*)d_in[11];
    const float* dec_bhh = (const float*)d_in[12];
    const float* outW    = (const float*)d_in[13];
    const float* outb    = (const float*)d_in[14];

    unsigned short* ws = (unsigned short*)d_ws;
    unsigned short* bWih_e = ws;                  // 3*H*H each
    unsigned short* bWhh_e = ws + 196608;
    unsigned short* bWih_d = ws + 2 * 196608;
    unsigned short* bWhh_d = ws + 3 * 196608;
    unsigned short* bEW_d  = ws + 4 * 196608;     // H*H
    unsigned short* bOWp   = ws + 4 * 196608 + 65536;  // 32*H

    const int n1 = 3 * HD * HD;
    const int n2 = HD * HD;
    cvt_bf16_kernel<<<(n1 + 255) / 256, 256, 0, stream>>>(encWih,  bWih_e, n1);
    cvt_bf16_kernel<<<(n1 + 255) / 256, 256, 0, stream>>>(encWhh,  bWhh_e, n1);
    cvt_bf16_kernel<<<(n1 + 255) / 256, 256, 0, stream>>>(decWihf, bWih_d, n1);
    cvt_bf16_kernel<<<(n1 + 255) / 256, 256, 0, stream>>>(decWhhf, bWhh_d, n1);
    cvt_bf16_kernel<<<(n2 + 255) / 256, 256, 0, stream>>>(decEWf,  bEW_d,  n2);
    pad_outw_kernel<<<(32 * HD + 255) / 256, 256, 0, stream>>>(outW, bOWp);

    gru_main<<<NBLK, NTHR, 0, stream>>>(
        x, eW, eb, bWih_e, bWhh_e, enc_bih, enc_bhh,
        bEW_d, dec_eb, bWih_d, bWhh_d, dec_bih, dec_bhh,
        bOWp, outb, (float*)d_out);
}

// Round 7
// 2624.553 us; speedup vs baseline: 2.7107x; 2.7107x over previous
//
#include <hip/hip_runtime.h>
#include <hip/hip_bf16.h>
#include <hip/hip_fp16.h>

#define HD    256
#define TENC  15
#define PLEN  45
#define MROW  64
#define NTHR  512
#define NBLK  (32768 / MROW)   // 512 blocks

typedef __attribute__((ext_vector_type(16))) float f32x16;
typedef __attribute__((ext_vector_type(8)))  short bf16x8;

#define MFMA32 __builtin_amdgcn_mfma_f32_32x32x16_bf16

__device__ __forceinline__ unsigned short f2bf(float f) {
    union { float f; unsigned int u; } v; v.f = f;
    unsigned int r = v.u + 0x7FFF + ((v.u >> 16) & 1);  // RNE
    return (unsigned short)(r >> 16);
}

// Transpose W[n_gcols][256] f32 -> bf16 in wave-burst layout:
// dst[seg*65536 + ((gc8*16 + kk)*64 + hi*32 + rowA)*8 + e]
// where seg=gcol>>8, gc=gcol&255, gc8=gc>>5, rowA=gc&31, hi=k-half,
// k = kk*16 + hi*8 + e. Main kernel's lane = hi*32 + rowA loads at
// lane*8 -> each (seg,gc8,kk) is one contiguous 1KB wave-burst.
__global__ void xpose_w_kernel(const float* __restrict__ src,
                               unsigned short* __restrict__ dst, int n_gcols) {
    int t = blockIdx.x * blockDim.x + threadIdx.x;
    if (t >= n_gcols * 32) return;
    int gcol = t >> 5, c8 = t & 31;
    int kk = c8 >> 1, hi = c8 & 1;
    const float* s = src + (size_t)gcol * HD + c8 * 8;
    int seg = gcol >> 8, gc = gcol & 255;
    size_t d = (size_t)seg * 65536 +
               ((size_t)(((gc >> 5) * 16 + kk) * 64 + hi * 32 + (gc & 31))) * 8;
    unsigned short v[8];
    #pragma unroll
    for (int e = 0; e < 8; ++e) v[e] = f2bf(s[e]);
    *(bf16x8*)(dst + d) = *(bf16x8*)v;
}

// outW [4][256] padded to 32 gate-cols, same layout (single seg, gc8=0)
__global__ void xpose_ow_kernel(const float* __restrict__ src,
                                unsigned short* __restrict__ dst) {
    int t = blockIdx.x * blockDim.x + threadIdx.x;
    if (t >= 32 * 32) return;
    int gcol = t >> 5, c8 = t & 31;
    int kk = c8 >> 1, hi = c8 & 1;
    unsigned short v[8];
    if (gcol < 4) {
        const float* s = src + (size_t)gcol * HD + c8 * 8;
        #pragma unroll
        for (int e = 0; e < 8; ++e) v[e] = f2bf(s[e]);
    } else {
        #pragma unroll
        for (int e = 0; e < 8; ++e) v[e] = 0;
    }
    size_t d = ((size_t)(kk * 64 + hi * 32 + gcol)) * 8;
    *(bf16x8*)(dst + d) = *(bf16x8*)v;
}

// Swizzled byte offset into a [64][256] bf16 LDS tile (row stride 512B).
// chunk ^= row&31: bijective per row; 32x32 A-frag ds_read_b128 spreads
// uniformly over all banks (2 lanes/bank = free, m136).
__device__ __forceinline__ int swz(int row, int col) {
    return row * 512 + ((((col >> 3) ^ row) & 31) << 4) + ((col & 7) << 1);
}

__global__ __launch_bounds__(NTHR, 2) void gru_main(
    const float* __restrict__ x,
    const float* __restrict__ eW, const float* __restrict__ eb,
    const unsigned short* __restrict__ encWih, const unsigned short* __restrict__ encWhh,
    const float* __restrict__ enc_bih, const float* __restrict__ enc_bhh,
    const unsigned short* __restrict__ decEW, const float* __restrict__ dec_eb,
    const unsigned short* __restrict__ decWih, const unsigned short* __restrict__ decWhh,
    const float* __restrict__ dec_bih, const float* __restrict__ dec_bhh,
    const unsigned short* __restrict__ outWt, const float* __restrict__ outb,
    float* __restrict__ out)
{
    __shared__ __align__(16) unsigned short ls_a[MROW * HD];  // 32KB swizzled bf16
    __shared__ __align__(16) unsigned short ls_h[MROW * HD];  // 32KB swizzled bf16
    __shared__ float ls_ew[HD * 4];
    __shared__ float ls_eb[HD];
    __shared__ float ls_bias[4 * HD];   // bR, bZ, bN(ih), bH(hh)
    __shared__ float ls_deb[HD];

    const int tid   = threadIdx.x;
    const int lane  = tid & 63;
    const int wv    = tid >> 6;      // 0..7
    const int rowA  = lane & 31;     // A-row within 32-row tile / C-col idx
    const int hi    = lane >> 5;     // k-half
    const int col   = wv * 32 + rowA;  // this lane's C/D gate column
    const int nbase = blockIdx.x * MROW;

    for (int i = tid; i < HD * 4; i += NTHR) ls_ew[i] = eW[i];
    if (tid < HD) {
        ls_eb[tid]            = eb[tid];
        ls_bias[tid]          = enc_bih[tid] + enc_bhh[tid];
        ls_bias[HD + tid]     = enc_bih[HD + tid] + enc_bhh[HD + tid];
        ls_bias[2 * HD + tid] = enc_bih[2 * HD + tid];
        ls_bias[3 * HD + tid] = enc_bhh[2 * HD + tid];
    }
    for (int i = tid; i < MROW * HD / 2; i += NTHR) ((unsigned int*)ls_h)[i] = 0u;

    // h carried as packed fp16: 2 rowtiles x 8 half2 = 16 regs (|h|<=1).
    __half2 hpk[16];
    #pragma unroll
    for (int i = 0; i < 16; ++i) hpk[i] = __floats2half2_rn(0.f, 0.f);

    f32x16 accR0, accR1, accZ0, accZ1, accN10, accN11, accN20, accN21;

    const char* pa = (const char*)ls_a + rowA * 512;
    const char* ph = (const char*)ls_h + rowA * 512;

    // gates: accR/Z += x@Wr/z + h@Ur/z ; accN1 += x@Wn ; accN2 += h@Un
    auto gates = [&](const unsigned short* Wi, const unsigned short* Wh) {
        accR0 = {}; accR1 = {}; accZ0 = {}; accZ1 = {};
        accN10 = {}; accN11 = {}; accN20 = {}; accN21 = {};
        const unsigned short* bi = Wi + wv * 8192 + lane * 8;
        const unsigned short* bh = Wh + wv * 8192 + lane * 8;
        #pragma unroll 2
        for (int kk = 0; kk < 16; ++kk) {
            const int sh = (((kk * 2 + hi) ^ rowA) & 31) << 4;
            bf16x8 ax0 = *(const bf16x8*)(pa + sh);
            bf16x8 ax1 = *(const bf16x8*)(pa + 16384 + sh);
            bf16x8 ah0 = *(const bf16x8*)(ph + sh);
            bf16x8 ah1 = *(const bf16x8*)(ph + 16384 + sh);
            const unsigned short* ki = bi + kk * 512;
            const unsigned short* kh = bh + kk * 512;
            bf16x8 bri = *(const bf16x8*)(ki);
            bf16x8 bzi = *(const bf16x8*)(ki + 65536);
            bf16x8 bni = *(const bf16x8*)(ki + 131072);
            bf16x8 brh = *(const bf16x8*)(kh);
            bf16x8 bzh = *(const bf16x8*)(kh + 65536);
            bf16x8 bnh = *(const bf16x8*)(kh + 131072);
            accR0  = MFMA32(ax0, bri, accR0, 0, 0, 0);
            accR1  = MFMA32(ax1, bri, accR1, 0, 0, 0);
            accZ0  = MFMA32(ax0, bzi, accZ0, 0, 0, 0);
            accZ1  = MFMA32(ax1, bzi, accZ1, 0, 0, 0);
            accN10 = MFMA32(ax0, bni, accN10, 0, 0, 0);
            accN11 = MFMA32(ax1, bni, accN11, 0, 0, 0);
            accR0  = MFMA32(ah0, brh, accR0, 0, 0, 0);
            accR1  = MFMA32(ah1, brh, accR1, 0, 0, 0);
            accZ0  = MFMA32(ah0, bzh, accZ0, 0, 0, 0);
            accZ1  = MFMA32(ah1, bzh, accZ1, 0, 0, 0);
            accN20 = MFMA32(ah0, bnh, accN20, 0, 0, 0);
            accN21 = MFMA32(ah1, bnh, accN21, 0, 0, 0);
        }
    };

    // C/D 32x32 layout: col = lane&31, row = (q&3) + 8*(q>>2) + 4*hi
    auto upd_tile = [&](f32x16& aR, f32x16& aZ, f32x16& aN1, f32x16& aN2, int rt) {
        const float bR = ls_bias[col];
        const float bZ = ls_bias[HD + col];
        const float bN = ls_bias[2 * HD + col];
        const float bH = ls_bias[3 * HD + col];
        #pragma unroll
        for (int q = 0; q < 16; q += 2) {
            float2 hv = __half22float2(hpk[rt * 8 + (q >> 1)]);
            float rr0 = 1.f / (1.f + __expf(-(aR[q] + bR)));
            float zz0 = 1.f / (1.f + __expf(-(aZ[q] + bZ)));
            float pre0 = aN1[q] + bN + rr0 * (aN2[q] + bH);
            float nn0 = 2.f / (1.f + __expf(-2.f * pre0)) - 1.f;
            float h0 = (1.f - zz0) * nn0 + zz0 * hv.x;
            float rr1 = 1.f / (1.f + __expf(-(aR[q + 1] + bR)));
            float zz1 = 1.f / (1.f + __expf(-(aZ[q + 1] + bZ)));
            float pre1 = aN1[q + 1] + bN + rr1 * (aN2[q + 1] + bH);
            float nn1 = 2.f / (1.f + __expf(-2.f * pre1)) - 1.f;
            float h1 = (1.f - zz1) * nn1 + zz1 * hv.y;
            hpk[rt * 8 + (q >> 1)] = __floats2half2_rn(h0, h1);
        }
    };

    auto write_h = [&]() {
        #pragma unroll
        for (int rt = 0; rt < 2; ++rt)
            #pragma unroll
            for (int q = 0; q < 16; q += 2) {
                float2 hv = __half22float2(hpk[rt * 8 + (q >> 1)]);
                int row = rt * 32 + (q & 3) + ((q >> 2) << 3) + (hi << 2);
                *(unsigned short*)((char*)ls_h + swz(row, col))     = f2bf(hv.x);
                *(unsigned short*)((char*)ls_h + swz(row + 1, col)) = f2bf(hv.y);
            }
    };

    auto embed_step = [&](int t) {
        int row = tid & 63;
        int c0  = (tid >> 6) * 32;
        const float4 xv = *(const float4*)(x + ((size_t)(nbase + row) * TENC + t) * 4);
        #pragma unroll 8
        for (int j = 0; j < 32; ++j) {
            int c = c0 + j;
            const float* wp = &ls_ew[c * 4];
            float v = fmaf(xv.x, wp[0], fmaf(xv.y, wp[1],
                      fmaf(xv.z, wp[2], fmaf(xv.w, wp[3], ls_eb[c]))));
            *(unsigned short*)((char*)ls_a + swz(row, c)) = f2bf(fmaxf(v, 0.f));
        }
    };

    // dec_in = relu(h @ dec_embed_W^T + deb) -> ls_a
    auto dec_embed = [&]() {
        f32x16 o0 = {}, o1 = {};
        const unsigned short* be = decEW + wv * 8192 + lane * 8;
        #pragma unroll 2
        for (int kk = 0; kk < 16; ++kk) {
            const int sh = (((kk * 2 + hi) ^ rowA) & 31) << 4;
            bf16x8 a0 = *(const bf16x8*)(ph + sh);
            bf16x8 a1 = *(const bf16x8*)(ph + 16384 + sh);
            bf16x8 b = *(const bf16x8*)(be + kk * 512);
            o0 = MFMA32(a0, b, o0, 0, 0, 0);
            o1 = MFMA32(a1, b, o1, 0, 0, 0);
        }
        const float db = ls_deb[col];
        #pragma unroll
        for (int rt = 0; rt < 2; ++rt) {
            const f32x16& o = rt ? o1 : o0;
            #pragma unroll
            for (int q = 0; q < 16; ++q) {
                int row = rt * 32 + (q & 3) + ((q >> 2) << 3) + (hi << 2);
                *(unsigned short*)((char*)ls_a + swz(row, col)) =
                    f2bf(fmaxf(o[q] + db, 0.f));
            }
        }
    };

    // out = h @ out_W^T + out_b; rowtile 0 -> wave 0, rowtile 1 -> wave 4
    auto out_layer = [&](int t) {
        if ((wv & 3) == 0) {
            const int rt = wv >> 2;
            f32x16 o = {};
            const unsigned short* bo = outWt + lane * 8;
            #pragma unroll 2
            for (int kk = 0; kk < 16; ++kk) {
                const int sh = (((kk * 2 + hi) ^ rowA) & 31) << 4;
                bf16x8 a = *(const bf16x8*)(ph + rt * 16384 + sh);
                bf16x8 b = *(const bf16x8*)(bo + kk * 512);
                o = MFMA32(a, b, o, 0, 0, 0);
            }
            if (rowA < 4) {
                const float bb = outb[rowA];
                #pragma unroll
                for (int q = 0; q < 16; ++q) {
                    int row = rt * 32 + (q & 3) + ((q >> 2) << 3) + (hi << 2);
                    out[((size_t)(nbase + row) * PLEN + t) * 4 + rowA] = o[q] + bb;
                }
            }
        }
    };

    // ---- prologue ----
    __syncthreads();             // staging + ls_h zero visible
    embed_step(0);
    __syncthreads();             // ls_a ready

    // ---- encoder: 2 barriers/step ----
    for (int t = 0; t < TENC; ++t) {
        gates(encWih, encWhh);
        upd_tile(accR0, accZ0, accN10, accN20, 0);
        upd_tile(accR1, accZ1, accN11, accN21, 1);
        __syncthreads();         // all ls_a/ls_h reads done
        write_h();
        if (t + 1 < TENC) embed_step(t + 1);
        __syncthreads();         // new h + next embed visible
    }

    // ---- encoder -> decoder transition ----
    if (tid < HD) {
        ls_bias[tid]          = dec_bih[tid] + dec_bhh[tid];
        ls_bias[HD + tid]     = dec_bih[HD + tid] + dec_bhh[HD + tid];
        ls_bias[2 * HD + tid] = dec_bih[2 * HD + tid];
        ls_bias[3 * HD + tid] = dec_bhh[2 * HD + tid];
        ls_deb[tid]           = dec_eb[tid];
    }
    __syncthreads();
    dec_embed();                 // dec_in0 from h_enc
    __syncthreads();

    // ---- decoder: 3 barriers/step ----
    for (int t = 0; t < PLEN; ++t) {
        gates(decWih, decWhh);   // reads ls_a (dec_in t), ls_h (h_{t-1})
        upd_tile(accR0, accZ0, accN10, accN20, 0);
        upd_tile(accR1, accZ1, accN11, accN21, 1);
        __syncthreads();         // B1: reads done
        write_h();               // h_t
        __syncthreads();         // B2: h_t visible
        dec_embed();             // dec_in t+1 -> ls_a
        out_layer(t);            // out_t from h_t
        __syncthreads();         // B3: ls_a ready
    }
}

extern "C" void kernel_launch(void* const* d_in, const int* in_sizes, int n_in,
                              void* d_out, int out_size, void* d_ws, size_t ws_size,
                              hipStream_t stream) {
    const float* x       = (const float*)d_in[0];
    const float* eW      = (const float*)d_in[1];
    const float* eb      = (const float*)d_in[2];
    const float* encWihf = (const float*)d_in[3];
    const float* encWhhf = (const float*)d_in[4];
    const float* enc_bih = (const float*)d_in[5];
    const float* enc_bhh = (const float*)d_in[6];
    const float* decEWf  = (const float*)d_in[7];
    const float* dec_eb  = (const float*)d_in[8];
    const float* decWihf = (const float*)d_in[9];
    const float* decWhhf = (const float*)d_in[10];
    const float* dec_bih = (const float*)d_in[11];
    const float* dec_bhh = (const float*)d_in[12];
    const float* outW    = (const float*)d_in[13];
    const float* outb    = (const float*)d_in[14];

    unsigned short* ws = (unsigned short*)d_ws;
    unsigned short* bWih_e = ws;                  // 3*H*H each
    unsigned short* bWhh_e = ws + 196608;
    unsigned short* bWih_d = ws + 2 * 196608;
    unsigned short* bWhh_d = ws + 3 * 196608;
    unsigned short* bEW_d  = ws + 4 * 196608;     // H*H
    unsigned short* bOWt   = ws + 4 * 196608 + 65536;  // 32*H

    const int t1 = 768 * 32;   // threads for 3-seg matrices
    const int t2 = 256 * 32;   // decEW
    xpose_w_kernel<<<(t1 + 255) / 256, 256, 0, stream>>>(encWihf, bWih_e, 768);
    xpose_w_kernel<<<(t1 + 255) / 256, 256, 0, stream>>>(encWhhf, bWhh_e, 768);
    xpose_w_kernel<<<(t1 + 255) / 256, 256, 0, stream>>>(decWihf, bWih_d, 768);
    xpose_w_kernel<<<(t1 + 255) / 256, 256, 0, stream>>>(decWhhf, bWhh_d, 768);
    xpose_w_kernel<<<(t2 + 255) / 256, 256, 0, stream>>>(decEWf,  bEW_d,  256);
    xpose_ow_kernel<<<4, 256, 0, stream>>>(outW, bOWt);

    gru_main<<<NBLK, NTHR, 0, stream>>>(
        x, eW, eb, bWih_e, bWhh_e, enc_bih, enc_bhh,
        bEW_d, dec_eb, bWih_d, bWhh_d, dec_bih, dec_bhh,
        bOWt, outb, (float*)d_out);
}

// Round 8
// 2279.384 us; speedup vs baseline: 3.1212x; 1.1514x over previous
//
#include <hip/hip_runtime.h>
#include <hip/hip_bf16.h>
#include <hip/hip_fp16.h>

#define HD    256
#define TENC  15
#define PLEN  45
#define MROW  64
#define NTHR  512
#define NBLK  (32768 / MROW)   // 512 blocks

typedef __attribute__((ext_vector_type(16))) float f32x16;
typedef __attribute__((ext_vector_type(8)))  short bf16x8;

#define MFMA32 __builtin_amdgcn_mfma_f32_32x32x16_bf16

__device__ __forceinline__ unsigned short f2bf(float f) {
    union { float f; unsigned int u; } v; v.f = f;
    unsigned int r = v.u + 0x7FFF + ((v.u >> 16) & 1);  // RNE
    return (unsigned short)(r >> 16);
}

// sigmoid / tanh without IEEE division (v_exp_f32 + v_rcp_f32 only)
__device__ __forceinline__ float fast_sig(float x) {
    float e = __builtin_amdgcn_exp2f(-1.44269504088896f * x);
    return __builtin_amdgcn_rcpf(1.f + e);
}
__device__ __forceinline__ float fast_tanh(float x) {
    float e = __builtin_amdgcn_exp2f(-2.88539008177793f * x);
    return (1.f - e) * __builtin_amdgcn_rcpf(1.f + e);
}

// Transpose W[n_gcols][256] f32 -> bf16 in wave-burst layout:
// dst[seg*65536 + ((gc8*16 + kk)*64 + hi*32 + rowA)*8 + e]
__global__ void xpose_w_kernel(const float* __restrict__ src,
                               unsigned short* __restrict__ dst, int n_gcols) {
    int t = blockIdx.x * blockDim.x + threadIdx.x;
    if (t >= n_gcols * 32) return;
    int gcol = t >> 5, c8 = t & 31;
    int kk = c8 >> 1, hi = c8 & 1;
    const float* s = src + (size_t)gcol * HD + c8 * 8;
    int seg = gcol >> 8, gc = gcol & 255;
    size_t d = (size_t)seg * 65536 +
               ((size_t)(((gc >> 5) * 16 + kk) * 64 + hi * 32 + (gc & 31))) * 8;
    unsigned short v[8];
    #pragma unroll
    for (int e = 0; e < 8; ++e) v[e] = f2bf(s[e]);
    *(bf16x8*)(dst + d) = *(bf16x8*)v;
}

// outW [4][256] padded to 32 gate-cols, same layout (single seg, gc8=0)
__global__ void xpose_ow_kernel(const float* __restrict__ src,
                                unsigned short* __restrict__ dst) {
    int t = blockIdx.x * blockDim.x + threadIdx.x;
    if (t >= 32 * 32) return;
    int gcol = t >> 5, c8 = t & 31;
    int kk = c8 >> 1, hi = c8 & 1;
    unsigned short v[8];
    if (gcol < 4) {
        const float* s = src + (size_t)gcol * HD + c8 * 8;
        #pragma unroll
        for (int e = 0; e < 8; ++e) v[e] = f2bf(s[e]);
    } else {
        #pragma unroll
        for (int e = 0; e < 8; ++e) v[e] = 0;
    }
    size_t d = ((size_t)(kk * 64 + hi * 32 + gcol)) * 8;
    *(bf16x8*)(dst + d) = *(bf16x8*)v;
}

// Swizzled byte offset into a [64][256] bf16 LDS tile (row stride 512B).
__device__ __forceinline__ int swz(int row, int col) {
    return row * 512 + ((((col >> 3) ^ row) & 31) << 4) + ((col & 7) << 1);
}

__global__ __launch_bounds__(NTHR, 2) void gru_main(
    const float* __restrict__ x,
    const float* __restrict__ eW, const float* __restrict__ eb,
    const unsigned short* __restrict__ encWih, const unsigned short* __restrict__ encWhh,
    const float* __restrict__ enc_bih, const float* __restrict__ enc_bhh,
    const unsigned short* __restrict__ decEW, const float* __restrict__ dec_eb,
    const unsigned short* __restrict__ decWih, const unsigned short* __restrict__ decWhh,
    const float* __restrict__ dec_bih, const float* __restrict__ dec_bhh,
    const unsigned short* __restrict__ outWt, const float* __restrict__ outb,
    float* __restrict__ out)
{
    __shared__ __align__(16) unsigned short ls_a[MROW * HD];  // 32KB swizzled bf16
    __shared__ __align__(16) unsigned short ls_h[MROW * HD];  // 32KB swizzled bf16
    __shared__ float ls_ew[HD * 4];
    __shared__ float ls_eb[HD];
    __shared__ float ls_bias[4 * HD];   // bR, bZ, bN(ih), bH(hh)
    __shared__ float ls_deb[HD];

    const int tid   = threadIdx.x;
    const int lane  = tid & 63;
    const int wv    = tid >> 6;      // 0..7
    const int rowA  = lane & 31;     // A-row within 32-row tile / C-col idx
    const int hi    = lane >> 5;     // k-half
    const int col   = wv * 32 + rowA;  // this lane's C/D gate column
    const int nbase = blockIdx.x * MROW;

    for (int i = tid; i < HD * 4; i += NTHR) ls_ew[i] = eW[i];
    if (tid < HD) {
        ls_eb[tid]            = eb[tid];
        ls_bias[tid]          = enc_bih[tid] + enc_bhh[tid];
        ls_bias[HD + tid]     = enc_bih[HD + tid] + enc_bhh[HD + tid];
        ls_bias[2 * HD + tid] = enc_bih[2 * HD + tid];
        ls_bias[3 * HD + tid] = enc_bhh[2 * HD + tid];
    }
    for (int i = tid; i < MROW * HD / 2; i += NTHR) ((unsigned int*)ls_h)[i] = 0u;

    // h carried as packed fp16: 2 rowtiles x 8 half2 = 16 regs (|h|<=1).
    __half2 hpk[16];
    #pragma unroll
    for (int i = 0; i < 16; ++i) hpk[i] = __floats2half2_rn(0.f, 0.f);

    // per-phase bias registers (encoder first, reloaded for decoder)
    float bR, bZ, bN, bH;

    f32x16 accR0, accR1, accZ0, accZ1, accN10, accN11, accN20, accN21;

    const char* pa = (const char*)ls_a + rowA * 512;
    const char* ph = (const char*)ls_h + rowA * 512;

    auto bcast = [](float v) {
        f32x16 a;
        #pragma unroll
        for (int i = 0; i < 16; ++i) a[i] = v;
        return a;
    };

    // gates: acc init = bias; accR/Z += x@Wr/z + h@Ur/z; accN1 += x@Wn; accN2 += h@Un
    auto gates = [&](const unsigned short* Wi, const unsigned short* Wh) {
        accR0 = bcast(bR);  accR1 = accR0;
        accZ0 = bcast(bZ);  accZ1 = accZ0;
        accN10 = bcast(bN); accN11 = accN10;
        accN20 = bcast(bH); accN21 = accN20;
        const unsigned short* bi = Wi + wv * 8192 + lane * 8;
        const unsigned short* bh = Wh + wv * 8192 + lane * 8;
        #pragma unroll 2
        for (int kk = 0; kk < 16; ++kk) {
            const int sh = (((kk * 2 + hi) ^ rowA) & 31) << 4;
            bf16x8 ax0 = *(const bf16x8*)(pa + sh);
            bf16x8 ax1 = *(const bf16x8*)(pa + 16384 + sh);
            bf16x8 ah0 = *(const bf16x8*)(ph + sh);
            bf16x8 ah1 = *(const bf16x8*)(ph + 16384 + sh);
            const unsigned short* ki = bi + kk * 512;
            const unsigned short* kh = bh + kk * 512;
            bf16x8 bri = *(const bf16x8*)(ki);
            bf16x8 bzi = *(const bf16x8*)(ki + 65536);
            bf16x8 bni = *(const bf16x8*)(ki + 131072);
            bf16x8 brh = *(const bf16x8*)(kh);
            bf16x8 bzh = *(const bf16x8*)(kh + 65536);
            bf16x8 bnh = *(const bf16x8*)(kh + 131072);
            accR0  = MFMA32(ax0, bri, accR0, 0, 0, 0);
            accR1  = MFMA32(ax1, bri, accR1, 0, 0, 0);
            accZ0  = MFMA32(ax0, bzi, accZ0, 0, 0, 0);
            accZ1  = MFMA32(ax1, bzi, accZ1, 0, 0, 0);
            accN10 = MFMA32(ax0, bni, accN10, 0, 0, 0);
            accN11 = MFMA32(ax1, bni, accN11, 0, 0, 0);
            accR0  = MFMA32(ah0, brh, accR0, 0, 0, 0);
            accR1  = MFMA32(ah1, brh, accR1, 0, 0, 0);
            accZ0  = MFMA32(ah0, bzh, accZ0, 0, 0, 0);
            accZ1  = MFMA32(ah1, bzh, accZ1, 0, 0, 0);
            accN20 = MFMA32(ah0, bnh, accN20, 0, 0, 0);
            accN21 = MFMA32(ah1, bnh, accN21, 0, 0, 0);
        }
    };

    // C/D 32x32 layout: col = lane&31, row = (q&3) + 8*(q>>2) + 4*hi
    auto upd_tile = [&](f32x16& aR, f32x16& aZ, f32x16& aN1, f32x16& aN2, int rt) {
        #pragma unroll
        for (int q = 0; q < 16; q += 2) {
            float2 hv = __half22float2(hpk[rt * 8 + (q >> 1)]);
            float r0 = fast_sig(aR[q]);
            float z0 = fast_sig(aZ[q]);
            float n0 = fast_tanh(fmaf(r0, aN2[q], aN1[q]));
            float h0 = fmaf(z0, hv.x - n0, n0);
            float r1 = fast_sig(aR[q + 1]);
            float z1 = fast_sig(aZ[q + 1]);
            float n1 = fast_tanh(fmaf(r1, aN2[q + 1], aN1[q + 1]));
            float h1 = fmaf(z1, hv.y - n1, n1);
            hpk[rt * 8 + (q >> 1)] = __floats2half2_rn(h0, h1);
        }
    };

    auto write_h = [&]() {
        #pragma unroll
        for (int rt = 0; rt < 2; ++rt)
            #pragma unroll
            for (int q = 0; q < 16; q += 2) {
                float2 hv = __half22float2(hpk[rt * 8 + (q >> 1)]);
                int row = rt * 32 + (q & 3) + ((q >> 2) << 3) + (hi << 2);
                *(unsigned short*)((char*)ls_h + swz(row, col))     = f2bf(hv.x);
                *(unsigned short*)((char*)ls_h + swz(row + 1, col)) = f2bf(hv.y);
            }
    };

    auto embed_step = [&](int t) {
        int row = tid & 63;
        int c0  = (tid >> 6) * 32;
        const float4 xv = *(const float4*)(x + ((size_t)(nbase + row) * TENC + t) * 4);
        #pragma unroll 8
        for (int j = 0; j < 32; ++j) {
            int c = c0 + j;
            const float* wp = &ls_ew[c * 4];
            float v = fmaf(xv.x, wp[0], fmaf(xv.y, wp[1],
                      fmaf(xv.z, wp[2], fmaf(xv.w, wp[3], ls_eb[c]))));
            *(unsigned short*)((char*)ls_a + swz(row, c)) = f2bf(fmaxf(v, 0.f));
        }
    };

    float deb;   // dec_embed bias for this lane's column (set at transition)

    // dec_in = relu(h @ dec_embed_W^T + deb) -> ls_a
    auto dec_embed = [&]() {
        f32x16 o0 = bcast(deb), o1 = o0;
        const unsigned short* be = decEW + wv * 8192 + lane * 8;
        #pragma unroll 2
        for (int kk = 0; kk < 16; ++kk) {
            const int sh = (((kk * 2 + hi) ^ rowA) & 31) << 4;
            bf16x8 a0 = *(const bf16x8*)(ph + sh);
            bf16x8 a1 = *(const bf16x8*)(ph + 16384 + sh);
            bf16x8 b = *(const bf16x8*)(be + kk * 512);
            o0 = MFMA32(a0, b, o0, 0, 0, 0);
            o1 = MFMA32(a1, b, o1, 0, 0, 0);
        }
        #pragma unroll
        for (int rt = 0; rt < 2; ++rt) {
            const f32x16& o = rt ? o1 : o0;
            #pragma unroll
            for (int q = 0; q < 16; ++q) {
                int row = rt * 32 + (q & 3) + ((q >> 2) << 3) + (hi << 2);
                *(unsigned short*)((char*)ls_a + swz(row, col)) =
                    f2bf(fmaxf(o[q], 0.f));
            }
        }
    };

    float bb;    // out bias for this lane (set before decoder loop)

    // out = h @ out_W^T + out_b; rowtile 0 -> wave 0, rowtile 1 -> wave 4
    auto out_layer = [&](int t) {
        if ((wv & 3) == 0) {
            const int rt = wv >> 2;
            f32x16 o = bcast(bb);
            const unsigned short* bo = outWt + lane * 8;
            #pragma unroll 2
            for (int kk = 0; kk < 16; ++kk) {
                const int sh = (((kk * 2 + hi) ^ rowA) & 31) << 4;
                bf16x8 a = *(const bf16x8*)(ph + rt * 16384 + sh);
                bf16x8 b = *(const bf16x8*)(bo + kk * 512);
                o = MFMA32(a, b, o, 0, 0, 0);
            }
            if (rowA < 4) {
                #pragma unroll
                for (int q = 0; q < 16; ++q) {
                    int row = rt * 32 + (q & 3) + ((q >> 2) << 3) + (hi << 2);
                    out[((size_t)(nbase + row) * PLEN + t) * 4 + rowA] = o[q];
                }
            }
        }
    };

    // ---- prologue ----
    __syncthreads();             // staging + ls_h zero visible
    bR = ls_bias[col];
    bZ = ls_bias[HD + col];
    bN = ls_bias[2 * HD + col];
    bH = ls_bias[3 * HD + col];
    embed_step(0);
    __syncthreads();             // ls_a ready

    // ---- encoder: 2 barriers/step ----
    for (int t = 0; t < TENC; ++t) {
        gates(encWih, encWhh);
        upd_tile(accR0, accZ0, accN10, accN20, 0);
        upd_tile(accR1, accZ1, accN11, accN21, 1);
        __syncthreads();         // all ls_a/ls_h reads done
        write_h();
        if (t + 1 < TENC) embed_step(t + 1);
        __syncthreads();         // new h + next embed visible
    }

    // ---- encoder -> decoder transition ----
    if (tid < HD) {
        ls_bias[tid]          = dec_bih[tid] + dec_bhh[tid];
        ls_bias[HD + tid]     = dec_bih[HD + tid] + dec_bhh[HD + tid];
        ls_bias[2 * HD + tid] = dec_bih[2 * HD + tid];
        ls_bias[3 * HD + tid] = dec_bhh[2 * HD + tid];
        ls_deb[tid]           = dec_eb[tid];
    }
    __syncthreads();
    bR = ls_bias[col];
    bZ = ls_bias[HD + col];
    bN = ls_bias[2 * HD + col];
    bH = ls_bias[3 * HD + col];
    deb = ls_deb[col];
    bb  = (rowA < 4) ? outb[rowA] : 0.f;
    dec_embed();                 // dec_in0 from h_enc
    __syncthreads();

    // ---- decoder: 3 barriers/step; out_layer hides under next gates ----
    for (int t = 0; t < PLEN; ++t) {
        gates(decWih, decWhh);   // reads ls_a (dec_in t), ls_h (h_{t-1})
        upd_tile(accR0, accZ0, accN10, accN20, 0);
        upd_tile(accR1, accZ1, accN11, accN21, 1);
        __syncthreads();         // B1: reads done
        write_h();               // h_t
        __syncthreads();         // B2: h_t visible
        dec_embed();             // dec_in t+1 -> ls_a
        __syncthreads();         // B3: ls_a ready
        out_layer(t);            // reads ls_h (stable until next write_h);
                                 // waves 1-3,5-7 proceed straight into gates(t+1)
    }
}

extern "C" void kernel_launch(void* const* d_in, const int* in_sizes, int n_in,
                              void* d_out, int out_size, void* d_ws, size_t ws_size,
                              hipStream_t stream) {
    const float* x       = (const float*)d_in[0];
    const float* eW      = (const float*)d_in[1];
    const float* eb      = (const float*)d_in[2];
    const float* encWihf = (const float*)d_in[3];
    const float* encWhhf = (const float*)d_in[4];
    const float* enc_bih = (const float*)d_in[5];
    const float* enc_bhh = (const float*)d_in[6];
    const float* decEWf  = (const float*)d_in[7];
    const float* dec_eb  = (const float*)d_in[8];
    const float* decWihf = (const float*)d_in[9];
    const float* decWhhf = (const float*)d_in[10];
    const float* dec_bih = (const float*)d_in[11];
    const float* dec_bhh = (const float*)d_in[12];
    const float* outW    = (const float*)d_in[13];
    const float* outb    = (const float*)d_in[14];

    unsigned short* ws = (unsigned short*)d_ws;
    unsigned short* bWih_e = ws;                  // 3*H*H each
    unsigned short* bWhh_e = ws + 196608;
    unsigned short* bWih_d = ws + 2 * 196608;
    unsigned short* bWhh_d = ws + 3 * 196608;
    unsigned short* bEW_d  = ws + 4 * 196608;     // H*H
    unsigned short* bOWt   = ws + 4 * 196608 + 65536;  // 32*H

    const int t1 = 768 * 32;   // threads for 3-seg matrices
    const int t2 = 256 * 32;   // decEW
    xpose_w_kernel<<<(t1 + 255) / 256, 256, 0, stream>>>(encWihf, bWih_e, 768);
    xpose_w_kernel<<<(t1 + 255) / 256, 256, 0, stream>>>(encWhhf, bWhh_e, 768);
    xpose_w_kernel<<<(t1 + 255) / 256, 256, 0, stream>>>(decWihf, bWih_d, 768);
    xpose_w_kernel<<<(t1 + 255) / 256, 256, 0, stream>>>(decWhhf, bWhh_d, 768);
    xpose_w_kernel<<<(t2 + 255) / 256, 256, 0, stream>>>(decEWf,  bEW_d,  256);
    xpose_ow_kernel<<<4, 256, 0, stream>>>(outW, bOWt);

    gru_main<<<NBLK, NTHR, 0, stream>>>(
        x, eW, eb, bWih_e, bWhh_e, enc_bih, enc_bhh,
        bEW_d, dec_eb, bWih_d, bWhh_d, dec_bih, dec_bhh,
        bOWt, outb, (float*)d_out);
}